// Round 4
// baseline (969.743 us; speedup 1.0000x reference)
//
#include <hip/hip_runtime.h>
#include <hip/hip_bf16.h>

using bf16 = __hip_bfloat16;
typedef __attribute__((ext_vector_type(8))) short bf16x8;
typedef __attribute__((ext_vector_type(4))) float f32x4;

#if defined(__has_builtin)
#if __has_builtin(__builtin_amdgcn_fdot2_f32_bf16)
#define HAVE_DOT2 1
typedef __attribute__((ext_vector_type(2))) __bf16 bf16x2v;
#endif
#endif

constexpr int N_   = 16384;
constexpr int E_   = 262144;
constexpr int F_   = 16;
constexpr int H_   = 128;
constexpr int QKV3_= 1536;   // q|k|v interleaved per node
constexpr int NFUSE_ = 1664; // q(512)|k(512)|v(512)|skip(128)
constexpr int DFF_ = 512;
constexpr int G_   = 128;
constexpr int L_   = 5;
constexpr float EPS_ = 1e-5f;

constexpr int WCATSZ = NFUSE_ * 128;   // 212992
constexpr int W1TSZ  = 512 * 128;      // 65536
constexpr int W2TSZ  = 512 * 128;      // 65536
constexpr int PER_L  = WCATSZ + W1TSZ + W2TSZ;

__device__ __forceinline__ float gelu_f(float x) {
  return 0.5f * x * (1.0f + erff(x * 0.70710678118654752440f));
}

__device__ __forceinline__ void unpack8(const uint4 w, float* f) {
  f[0] = __uint_as_float(w.x << 16); f[1] = __uint_as_float(w.x & 0xFFFF0000u);
  f[2] = __uint_as_float(w.y << 16); f[3] = __uint_as_float(w.y & 0xFFFF0000u);
  f[4] = __uint_as_float(w.z << 16); f[5] = __uint_as_float(w.z & 0xFFFF0000u);
  f[6] = __uint_as_float(w.w << 16); f[7] = __uint_as_float(w.w & 0xFFFF0000u);
}

__device__ __forceinline__ float qk_dot(const uint4 kw, const uint4 qw, const float* qf) {
#ifdef HAVE_DOT2
  union U { unsigned u; bf16x2v v; };
  U a0, a1, a2, a3, b0, b1, b2, b3;
  a0.u = kw.x; a1.u = kw.y; a2.u = kw.z; a3.u = kw.w;
  b0.u = qw.x; b1.u = qw.y; b2.u = qw.z; b3.u = qw.w;
  float p = 0.f;
  p = __builtin_amdgcn_fdot2_f32_bf16(a0.v, b0.v, p, false);
  p = __builtin_amdgcn_fdot2_f32_bf16(a1.v, b1.v, p, false);
  p = __builtin_amdgcn_fdot2_f32_bf16(a2.v, b2.v, p, false);
  p = __builtin_amdgcn_fdot2_f32_bf16(a3.v, b3.v, p, false);
  return p;
#else
  float kf[8]; unpack8(kw, kf);
  return kf[0] * qf[0] + kf[1] * qf[1] + kf[2] * qf[2] + kf[3] * qf[3]
       + kf[4] * qf[4] + kf[5] * qf[5] + kf[6] * qf[6] + kf[7] * qf[7];
#endif
}

// ---------------- weight transpose+cast prep (once per call) ----------------
__global__ void k_prep(const float* __restrict__ Wq, const float* __restrict__ Wk,
                       const float* __restrict__ Wv, const float* __restrict__ Ws,
                       const float* __restrict__ W1, const float* __restrict__ W2,
                       const float* __restrict__ bq, const float* __restrict__ bk,
                       const float* __restrict__ bv, const float* __restrict__ bs,
                       bf16* __restrict__ Wcat, bf16* __restrict__ W1t,
                       bf16* __restrict__ W2t, float* __restrict__ bcat) {
  int idx = blockIdx.x * 256 + threadIdx.x;
  const int total = 5 * PER_L;
  if (idx < total) {
    int l = idx / PER_L, t = idx % PER_L;
    if (t < WCATSZ) {
      int n = t >> 7, kk = t & 127;
      float v;
      if (n < 512)       v = Wq[((size_t)l * 128 + kk) * 512 + n];
      else if (n < 1024) v = Wk[((size_t)l * 128 + kk) * 512 + n - 512];
      else if (n < 1536) v = Wv[((size_t)l * 128 + kk) * 512 + n - 1024];
      else               v = Ws[((size_t)l * 128 + kk) * 128 + n - 1536];
      Wcat[(size_t)l * WCATSZ + t] = __float2bfloat16(v);
    } else if (t < WCATSZ + W1TSZ) {
      int u = t - WCATSZ; int n = u >> 7, kk = u & 127;   // W1t[n][kk], n<512
      W1t[(size_t)l * W1TSZ + u] = __float2bfloat16(W1[((size_t)l * 128 + kk) * 512 + n]);
    } else {
      int u = t - WCATSZ - W1TSZ; int n = u >> 9, kk = u & 511;  // W2t[n][kk], n<128
      W2t[(size_t)l * W2TSZ + u] = __float2bfloat16(W2[((size_t)l * 512 + kk) * 128 + n]);
    }
  } else {
    int j = idx - total;
    if (j < 5 * NFUSE_) {
      int l = j / NFUSE_, c = j % NFUSE_;
      float v = (c < 512)  ? bq[l * 512 + c]
              : (c < 1024) ? bk[l * 512 + c - 512]
              : (c < 1536) ? bv[l * 512 + c - 1024]
              :              bs[l * 128 + c - 1536];
      bcat[j] = v;
    }
  }
}

// ---------------- embedding GEMM + fused BN partial stats ----------------
__global__ __launch_bounds__(256) void k_embed2(const float* __restrict__ x,
    const float* __restrict__ W, const float* __restrict__ b,
    float* __restrict__ out, float* __restrict__ ss, float* __restrict__ sq) {
  __shared__ float xs[128][16];
  __shared__ float wsm[16][128];
  __shared__ float sr[2][128], qr[2][128];
  const int blk = blockIdx.x;          // 128 blocks x 128 rows
  const int t = threadIdx.x;
  for (int i = t; i < 16 * 128; i += 256) wsm[i >> 7][i & 127] = W[i];
  for (int i = t; i < 128 * 16; i += 256) xs[i >> 4][i & 15] = x[(size_t)blk * 2048 + i];
  __syncthreads();
  const int c = t & 127, rg = t >> 7;
  float bc = b[c];
  float s = 0.f, q = 0.f;
  for (int r = rg * 64; r < rg * 64 + 64; ++r) {
    float v = bc;
#pragma unroll
    for (int f = 0; f < 16; ++f) v = fmaf(xs[r][f], wsm[f][c], v);
    out[(size_t)(blk * 128 + r) * 128 + c] = v;
    s += v; q += v * v;
  }
  sr[rg][c] = s; qr[rg][c] = q;
  __syncthreads();
  if (t < 128) { ss[blk * 128 + t] = sr[0][t] + sr[1][t]; sq[blk * 128 + t] = qr[0][t] + qr[1][t]; }
}

// ---------------- BatchNorm finalize / apply ----------------
template<int NC>
__global__ void k_bn_finalize(const float* __restrict__ sums, const float* __restrict__ sumsq,
                              const float* __restrict__ g, const float* __restrict__ be,
                              float* __restrict__ a, float* __restrict__ cc) {
  int c = blockIdx.x * 128 + threadIdx.x;
  if (c >= NC) return;
  float s = 0.f, q = 0.f;
  for (int b = 0; b < 128; ++b) { s += sums[b * NC + c]; q += sumsq[b * NC + c]; }
  float mean = s * (1.0f / N_);
  float var  = q * (1.0f / N_) - mean * mean;
  float inv  = rsqrtf(var + EPS_);
  float aa   = g[c] * inv;
  a[c]  = aa;
  cc[c] = be[c] - aa * mean;
}

// vectorized x4: one float4 in, 4 bf16 out per thread
template<int NC>
__global__ void k_bn_apply_gelu_cast(const float* __restrict__ xin, const float* __restrict__ a,
                                     const float* __restrict__ cc, bf16* __restrict__ outb) {
  int i4 = (blockIdx.x * 256 + threadIdx.x) * 4;
  int c = i4 & (NC - 1);
  float4 v = *reinterpret_cast<const float4*>(xin + i4);
  union { uint2 u2; bf16 h[4]; } pk;
  pk.h[0] = __float2bfloat16(gelu_f(fmaf(a[c + 0], v.x, cc[c + 0])));
  pk.h[1] = __float2bfloat16(gelu_f(fmaf(a[c + 1], v.y, cc[c + 1])));
  pk.h[2] = __float2bfloat16(gelu_f(fmaf(a[c + 2], v.z, cc[c + 2])));
  pk.h[3] = __float2bfloat16(gelu_f(fmaf(a[c + 3], v.w, cc[c + 3])));
  *reinterpret_cast<uint2*>(outb + i4) = pk.u2;
}

// ---------------- CSR build over dst ----------------
__global__ void k_count(const int* __restrict__ dst, int* __restrict__ deg) {
  int e = blockIdx.x * 256 + threadIdx.x;
  if (e < E_) atomicAdd(&deg[dst[e]], 1);
}

__global__ void k_bsum(const int* __restrict__ deg, int* __restrict__ bsum) {
  __shared__ int sh[256];
  int t = threadIdx.x;
  sh[t] = deg[blockIdx.x * 256 + t];
  __syncthreads();
  for (int d = 128; d > 0; d >>= 1) { if (t < d) sh[t] += sh[t + d]; __syncthreads(); }
  if (t == 0) bsum[blockIdx.x] = sh[0];
}

__global__ void k_btop(const int* __restrict__ bsum, int* __restrict__ btop) {
  int t = threadIdx.x;          // 64 threads, one wave
  int v = bsum[t];
  int s = v;
  for (int d = 1; d < 64; d <<= 1) { int o = __shfl_up(s, d); if (t >= d) s += o; }
  btop[t] = s - v;              // exclusive
}

__global__ void k_boffs(const int* __restrict__ deg, const int* __restrict__ btop,
                        int* __restrict__ offs) {
  __shared__ int sh[256];
  int t = threadIdx.x;
  int v = deg[blockIdx.x * 256 + t];
  sh[t] = v;
  __syncthreads();
  for (int d = 1; d < 256; d <<= 1) {
    int add = (t >= d) ? sh[t - d] : 0;
    __syncthreads();
    sh[t] += add;
    __syncthreads();
  }
  offs[blockIdx.x * 256 + t] = btop[blockIdx.x] + sh[t] - v;
  if (blockIdx.x == 63 && t == 255) offs[N_] = E_;
}

__global__ void k_scatter(const int* __restrict__ src, const int* __restrict__ dst,
                          const int* __restrict__ off, int* __restrict__ cursor,
                          int* __restrict__ srcs) {
  int e = blockIdx.x * 256 + threadIdx.x;
  if (e < E_) {
    int d = dst[e];
    int pos = off[d] + atomicAdd(&cursor[d], 1);
    srcs[pos] = src[e];
  }
}

// sort each node's adjacency by src (ascending) -> quasi-streaming gathers
__global__ __launch_bounds__(128) void k_sortadj(const int* __restrict__ off,
                                                 int* __restrict__ srcs) {
  __shared__ int buf[128][65];
  int n = blockIdx.x * 128 + threadIdx.x;
  int s0 = off[n];
  int d = off[n + 1] - s0;
  if (d > 64) d = 64;     // Poisson(16): P(d>64) ~ 0; partial sort is still correct math
  int* row = buf[threadIdx.x];
  for (int i = 0; i < d; ++i) row[i] = srcs[s0 + i];
  for (int i = 1; i < d; ++i) {
    int key = row[i];
    int j = i - 1;
    while (j >= 0 && row[j] > key) { row[j + 1] = row[j]; --j; }
    row[j + 1] = key;
  }
  for (int i = 0; i < d; ++i) srcs[s0 + i] = row[i];
}

// ---------------- bf16 MFMA GEMM: C[M,NOUT] = A[M,K] @ BT[NOUT,K]^T + bias ----------------
// MODE 0: fp32 out. MODE 1: fp32 + bf16 out. MODE 2: fused qkv routing.
// MODE 3: fp32 out + per-m-tile BN column partial stats.
template<int KDIM, int NOUT, int TM, int MODE>
__global__ __launch_bounds__(256) void k_mfma(
    const bf16* __restrict__ A, const bf16* __restrict__ BT,
    const float* __restrict__ bias,
    float* __restrict__ outF, bf16* __restrict__ outB,
    bf16* __restrict__ QKVp, float* __restrict__ xrp,
    float* __restrict__ ss, float* __restrict__ sq) {
  constexpr int MF = TM / 32;
  __shared__ bf16 As[TM][72];
  __shared__ bf16 Bs[128][72];
  __shared__ float sred[2][128], qred[2][128];
  const int tid = threadIdx.x;
  const int wid = tid >> 6, lane = tid & 63;
  const int wr = wid >> 1, wc = wid & 1;
  const int m0 = blockIdx.x * TM, n0 = blockIdx.y * 128;
  const int ln = lane & 15, lq = lane >> 4;
  f32x4 acc[MF][4];
#pragma unroll
  for (int i = 0; i < MF; ++i)
#pragma unroll
    for (int j = 0; j < 4; ++j) acc[i][j] = (f32x4){0.f, 0.f, 0.f, 0.f};

  for (int k0 = 0; k0 < KDIM; k0 += 64) {
#pragma unroll
    for (int u = tid; u < TM * 8; u += 256) {
      int r = u >> 3, c = u & 7;
      *(uint4*)(&As[r][c * 8]) = *(const uint4*)(A + (size_t)(m0 + r) * KDIM + k0 + c * 8);
    }
#pragma unroll
    for (int u = tid; u < 1024; u += 256) {
      int r = u >> 3, c = u & 7;
      *(uint4*)(&Bs[r][c * 8]) = *(const uint4*)(BT + (size_t)(n0 + r) * KDIM + k0 + c * 8);
    }
    __syncthreads();
#pragma unroll
    for (int kk = 0; kk < 2; ++kk) {
      bf16x8 af[MF], bg[4];
#pragma unroll
      for (int i = 0; i < MF; ++i)
        af[i] = *(const bf16x8*)(&As[wr * (TM / 2) + i * 16 + ln][kk * 32 + lq * 8]);
#pragma unroll
      for (int j = 0; j < 4; ++j)
        bg[j] = *(const bf16x8*)(&Bs[wc * 64 + j * 16 + ln][kk * 32 + lq * 8]);
#pragma unroll
      for (int i = 0; i < MF; ++i)
#pragma unroll
        for (int j = 0; j < 4; ++j)
          acc[i][j] = __builtin_amdgcn_mfma_f32_16x16x32_bf16(af[i], bg[j], acc[i][j], 0, 0, 0);
    }
    __syncthreads();
  }
  float ssj[4] = {0.f, 0.f, 0.f, 0.f}, sqj[4] = {0.f, 0.f, 0.f, 0.f};
#pragma unroll
  for (int i = 0; i < MF; ++i) {
#pragma unroll
    for (int j = 0; j < 4; ++j) {
      int gcol = n0 + wc * 64 + j * 16 + ln;
      float bv = bias[gcol];
      int row0 = m0 + wr * (TM / 2) + i * 16 + lq * 4;
#pragma unroll
      for (int qq = 0; qq < 4; ++qq) {
        float val = acc[i][j][qq] + bv;
        int row = row0 + qq;
        if (MODE == 0 || MODE == 3) {
          outF[(size_t)row * NOUT + gcol] = val;
          if (MODE == 3) { ssj[j] += val; sqj[j] += val * val; }
        } else if (MODE == 1) {
          outF[(size_t)row * NOUT + gcol] = val;
          outB[(size_t)row * NOUT + gcol] = __float2bfloat16(val);
        } else {
          if (n0 < 1536) QKVp[(size_t)row * QKV3_ + gcol] = __float2bfloat16(val);
          else           xrp[(size_t)row * H_ + (gcol - 1536)] = val;
        }
      }
    }
  }
  if constexpr (MODE == 3) {
#pragma unroll
    for (int j = 0; j < 4; ++j) {
      ssj[j] += __shfl_xor(ssj[j], 16); ssj[j] += __shfl_xor(ssj[j], 32);
      sqj[j] += __shfl_xor(sqj[j], 16); sqj[j] += __shfl_xor(sqj[j], 32);
    }
    if (lq == 0) {
#pragma unroll
      for (int j = 0; j < 4; ++j) {
        sred[wr][wc * 64 + j * 16 + ln] = ssj[j];
        qred[wr][wc * 64 + j * 16 + ln] = sqj[j];
      }
    }
    __syncthreads();
    if (tid < 128) {
      ss[(size_t)blockIdx.x * NOUT + n0 + tid] = sred[0][tid] + sred[1][tid];
      sq[(size_t)blockIdx.x * NOUT + n0 + tid] = qred[0][tid] + qred[1][tid];
    }
  }
}

// ---------------- fused attention + beta gate (one wave per dst node) ----------------
__global__ __launch_bounds__(256) void k_attn(const bf16* __restrict__ QKV,
    const float* __restrict__ xr, const float* __restrict__ Wb,
    const int* __restrict__ srcs, const int* __restrict__ off,
    bf16* __restrict__ gated) {
  const int wave = threadIdx.x >> 6;
  const int lane = threadIdx.x & 63;
  // XCD-aware swizzle: each XCD gets a contiguous 2048-node chunk
  const int bid = blockIdx.x;
  const int swz = ((bid & 7) << 9) | (bid >> 3);   // 4096 blocks, bijective
  const int node = swz * 4 + wave;
  const float scale = 0.08838834764831845f;   // 1/sqrt(128)
  const uint4* qp = reinterpret_cast<const uint4*>(QKV + (size_t)node * QKV3_);
  uint4 qw = qp[lane];
  float qf[8];
#ifndef HAVE_DOT2
  unpack8(qw, qf);
#else
  qf[0] = 0.f;   // unused
#endif
  float m = -1e30f, den = 0.f;
  float acc[8] = {0.f, 0.f, 0.f, 0.f, 0.f, 0.f, 0.f, 0.f};
  const int s0 = off[node], s1 = off[node + 1];
  if (s0 < s1) {
    int i0 = srcs[s0];
    int i1 = (s0 + 1 < s1) ? srcs[s0 + 1] : i0;
    const uint4* p0 = reinterpret_cast<const uint4*>(QKV + (size_t)i0 * QKV3_ + 512) + lane;
    const uint4* p1 = reinterpret_cast<const uint4*>(QKV + (size_t)i1 * QKV3_ + 512) + lane;
    uint4 k0 = p0[0], v0 = p0[64];
    uint4 k1 = p1[0], v1 = p1[64];
    for (int t = s0; t < s1; t += 2) {
      // prefetch edges t+2, t+3 (clamped addresses -> cache hits on tail)
      int j0 = (t + 2 < s1) ? srcs[t + 2] : i0;
      int j1 = (t + 3 < s1) ? srcs[t + 3] : i0;
      const uint4* q0 = reinterpret_cast<const uint4*>(QKV + (size_t)j0 * QKV3_ + 512) + lane;
      const uint4* q1 = reinterpret_cast<const uint4*>(QKV + (size_t)j1 * QKV3_ + 512) + lane;
      uint4 nk0 = q0[0], nv0 = q0[64];
      uint4 nk1 = q1[0], nv1 = q1[64];
      {
        float p = qk_dot(k0, qw, qf);
        p += __shfl_xor(p, 1); p += __shfl_xor(p, 2);
        p += __shfl_xor(p, 4); p += __shfl_xor(p, 8);
        float logit = p * scale;
        if (logit > m + 8.f) {        // defer-max: rescale only on big jumps
          float co = __expf(m - logit);
          den *= co;
#pragma unroll
          for (int j = 0; j < 8; ++j) acc[j] *= co;
          m = logit;
        }
        float pe = __expf(logit - m);
        den += pe;
        float vf[8]; unpack8(v0, vf);
#pragma unroll
        for (int j = 0; j < 8; ++j) acc[j] = fmaf(pe, vf[j], acc[j]);
      }
      if (t + 1 < s1) {
        float p = qk_dot(k1, qw, qf);
        p += __shfl_xor(p, 1); p += __shfl_xor(p, 2);
        p += __shfl_xor(p, 4); p += __shfl_xor(p, 8);
        float logit = p * scale;
        if (logit > m + 8.f) {
          float co = __expf(m - logit);
          den *= co;
#pragma unroll
          for (int j = 0; j < 8; ++j) acc[j] *= co;
          m = logit;
        }
        float pe = __expf(logit - m);
        den += pe;
        float vf[8]; unpack8(v1, vf);
#pragma unroll
        for (int j = 0; j < 8; ++j) acc[j] = fmaf(pe, vf[j], acc[j]);
      }
      k0 = nk0; v0 = nv0; k1 = nk1; v1 = nv1;
    }
  }
  float inv = 1.f / (den + 1e-16f);
  float r[8];
#pragma unroll
  for (int j = 0; j < 8; ++j) {
    r[j] = acc[j] * inv;
    r[j] += __shfl_xor(r[j], 16);
    r[j] += __shfl_xor(r[j], 32);
    r[j] *= 0.25f;                 // mean over 4 heads; all lanes hold result
  }
  // fused beta gate
  const int c0 = (lane & 15) * 8;
  float xv[8];
  const float* xp = xr + (size_t)node * H_ + c0;
#pragma unroll
  for (int j = 0; j < 8; ++j) xv[j] = xp[j];
  float s = 0.f;
#pragma unroll
  for (int j = 0; j < 8; ++j) {
    int c = c0 + j;
    s += r[j] * (Wb[c] + Wb[256 + c]) + xv[j] * (Wb[128 + c] - Wb[256 + c]);
  }
  s += __shfl_xor(s, 1); s += __shfl_xor(s, 2);
  s += __shfl_xor(s, 4); s += __shfl_xor(s, 8);
  float beta = 1.f / (1.f + __expf(-s));
  if (lane < 16) {
    union { uint4 u4; bf16 h[8]; } pk;
#pragma unroll
    for (int j = 0; j < 8; ++j) pk.h[j] = __float2bfloat16(beta * xv[j] + (1.f - beta) * r[j]);
    *reinterpret_cast<uint4*>(gated + (size_t)node * H_ + c0) = pk.u4;
  }
}

// ---------------- graph max-pool + prediction ----------------
__global__ void k_pool_init(unsigned int* __restrict__ pooled) {
  int i = blockIdx.x * 64 + threadIdx.x;
  if (i < G_ * H_) pooled[i] = 0x007FFFFFu;
}

__global__ void k_pool(const float* __restrict__ h, const int* __restrict__ batch,
                       unsigned int* __restrict__ pooled) {
  int idx = blockIdx.x * 256 + threadIdx.x;
  int n = idx >> 7, c = idx & 127;
  unsigned u = __float_as_uint(h[idx]);
  u = (u & 0x80000000u) ? ~u : (u | 0x80000000u);
  atomicMax(&pooled[batch[n] * H_ + c], u);
}

__global__ void k_pred(const unsigned int* __restrict__ pooled, const float* __restrict__ predW,
                       const float* __restrict__ predb, float* __restrict__ out) {
  int g = blockIdx.x;
  int lane = threadIdx.x;
  float s = 0.f;
  for (int c = lane; c < H_; c += 64) {
    unsigned u = pooled[g * H_ + c];
    u = (u & 0x80000000u) ? (u & 0x7FFFFFFFu) : ~u;
    s += __uint_as_float(u) * predW[c];
  }
#pragma unroll
  for (int d = 1; d < 64; d <<= 1) s += __shfl_xor(s, d);
  if (lane == 0) out[g] = s + predb[0];
}

extern "C" void kernel_launch(void* const* d_in, const int* in_sizes, int n_in,
                              void* d_out, int out_size, void* d_ws, size_t ws_size,
                              hipStream_t stream) {
  const float* x      = (const float*)d_in[0];
  const int*   edge   = (const int*)d_in[1];
  const int*   esrc   = edge;
  const int*   edst   = edge + E_;
  const int*   batch  = (const int*)d_in[2];
  const float* embW   = (const float*)d_in[3];
  const float* embb   = (const float*)d_in[4];
  const float* emb_g  = (const float*)d_in[5];
  const float* emb_be = (const float*)d_in[6];
  const float* Wq     = (const float*)d_in[7];
  const float* bq     = (const float*)d_in[8];
  const float* Wk     = (const float*)d_in[9];
  const float* bk     = (const float*)d_in[10];
  const float* Wv     = (const float*)d_in[11];
  const float* bv     = (const float*)d_in[12];
  const float* Wskip  = (const float*)d_in[13];
  const float* bskip  = (const float*)d_in[14];
  const float* Wbeta  = (const float*)d_in[15];
  const float* W1     = (const float*)d_in[16];
  const float* b1     = (const float*)d_in[17];
  const float* g1     = (const float*)d_in[18];
  const float* be1    = (const float*)d_in[19];
  const float* W2     = (const float*)d_in[20];
  const float* b2     = (const float*)d_in[21];
  const float* predW  = (const float*)d_in[22];
  const float* predb  = (const float*)d_in[23];

  // ---- workspace layout ----
  float* ws = (float*)d_ws;
  size_t o = 0;
  auto alloc_f = [&](size_t n) { float* p = ws + o; o += n; return p; };
  float* h32   = alloc_f((size_t)N_ * H_);
  float* t1    = alloc_f((size_t)N_ * DFF_);
  float* xr    = alloc_f((size_t)N_ * H_);
  float* stats = alloc_f(2 * 128 * DFF_);
  float* a_c   = alloc_f(DFF_);
  float* c_c   = alloc_f(DFF_);
  float* bcat  = alloc_f(5 * NFUSE_);
  bf16* bp = (bf16*)(ws + o);
  size_t ob = 0;
  auto alloc_b = [&](size_t n) { bf16* p = bp + ob; ob += n; return p; };
  bf16* QKV  = alloc_b((size_t)N_ * QKV3_);
  bf16* hb   = alloc_b((size_t)N_ * H_);
  bf16* gated= alloc_b((size_t)N_ * H_);
  bf16* t1b  = alloc_b((size_t)N_ * DFF_);
  bf16* Wcat = alloc_b((size_t)5 * WCATSZ);
  bf16* W1t  = alloc_b((size_t)5 * W1TSZ);
  bf16* W2t  = alloc_b((size_t)5 * W2TSZ);
  unsigned int* pooled = (unsigned int*)(bp + ob);
  int* deg    = (int*)(pooled + G_ * H_);
  int* offs   = deg + N_;
  int* cursor = offs + N_ + 1;
  int* srcs   = cursor + N_;
  int* bsum   = srcs + E_;       // 64
  int* btop   = bsum + 64;       // 64

  // ---- weight prep ----
  int prep_total = 5 * PER_L + 5 * NFUSE_;
  k_prep<<<(prep_total + 255) / 256, 256, 0, stream>>>(Wq, Wk, Wv, Wskip, W1, W2,
                                                       bq, bk, bv, bskip, Wcat, W1t, W2t, bcat);

  // ---- CSR build (hierarchical scan) + per-node src sort ----
  hipMemsetAsync(deg, 0, N_ * sizeof(int), stream);
  hipMemsetAsync(cursor, 0, N_ * sizeof(int), stream);
  k_count  <<<E_ / 256, 256, 0, stream>>>(edst, deg);
  k_bsum   <<<64, 256, 0, stream>>>(deg, bsum);
  k_btop   <<<1, 64, 0, stream>>>(bsum, btop);
  k_boffs  <<<64, 256, 0, stream>>>(deg, btop, offs);
  k_scatter<<<E_ / 256, 256, 0, stream>>>(esrc, edst, offs, cursor, srcs);
  k_sortadj<<<N_ / 128, 128, 0, stream>>>(offs, srcs);

  // ---- embedding (+fused stats) + BN + GELU -> bf16 ----
  k_embed2<<<128, 256, 0, stream>>>(x, embW, embb, t1, stats, stats + 128 * 128);
  k_bn_finalize<128><<<1, 128, 0, stream>>>(stats, stats + 128 * 128, emb_g, emb_be, a_c, c_c);
  k_bn_apply_gelu_cast<128><<<N_ * H_ / 1024, 256, 0, stream>>>(t1, a_c, c_c, hb);

  for (int l = 0; l < L_; ++l) {
    const float* Wb_ = Wbeta + (size_t)l * 3 * H_;
    const float* b1_ = b1 + (size_t)l * DFF_;
    const float* g1_ = g1 + (size_t)l * DFF_;
    const float* be1_= be1 + (size_t)l * DFF_;
    const float* b2_ = b2 + (size_t)l * H_;

    k_mfma<128, NFUSE_, 128, 2><<<dim3(N_ / 128, NFUSE_ / 128), 256, 0, stream>>>(
        hb, Wcat + (size_t)l * WCATSZ, bcat + (size_t)l * NFUSE_,
        nullptr, nullptr, QKV, xr, nullptr, nullptr);

    k_attn<<<N_ / 4, 256, 0, stream>>>(QKV, xr, Wb_, srcs, offs, gated);

    k_mfma<128, 512, 128, 3><<<dim3(N_ / 128, 4), 256, 0, stream>>>(
        gated, W1t + (size_t)l * W1TSZ, b1_, t1, nullptr, nullptr, nullptr,
        stats, stats + 128 * 512);

    k_bn_finalize<512><<<4, 128, 0, stream>>>(stats, stats + 128 * 512, g1_, be1_, a_c, c_c);
    k_bn_apply_gelu_cast<512><<<N_ * DFF_ / 1024, 256, 0, stream>>>(t1, a_c, c_c, t1b);

    k_mfma<512, 128, 64, 1><<<dim3(N_ / 64, 1), 256, 0, stream>>>(
        t1b, W2t + (size_t)l * W2TSZ, b2_, h32, hb, nullptr, nullptr, nullptr, nullptr);
  }

  // ---- pooling + prediction ----
  k_pool_init<<<G_ * H_ / 64, 64, 0, stream>>>(pooled);
  k_pool<<<N_ * H_ / 256, 256, 0, stream>>>(h32, batch, pooled);
  k_pred<<<G_, 64, 0, stream>>>(pooled, predW, predb, (float*)d_out);
}

// Round 5
// 946.336 us; speedup vs baseline: 1.0247x; 1.0247x over previous
//
#include <hip/hip_runtime.h>
#include <hip/hip_bf16.h>

using bf16 = __hip_bfloat16;
typedef __attribute__((ext_vector_type(8))) short bf16x8;
typedef __attribute__((ext_vector_type(4))) float f32x4;

#if defined(__has_builtin)
#if __has_builtin(__builtin_amdgcn_fdot2_f32_bf16)
#define HAVE_DOT2 1
typedef __attribute__((ext_vector_type(2))) __bf16 bf16x2v;
#endif
#endif

constexpr int N_   = 16384;
constexpr int E_   = 262144;
constexpr int F_   = 16;
constexpr int H_   = 128;
constexpr int QKV3_= 1536;   // q|k|v interleaved per node
constexpr int NFUSE_ = 1664; // q(512)|k(512)|v(512)|skip(128)
constexpr int DFF_ = 512;
constexpr int G_   = 128;
constexpr int L_   = 5;
constexpr float EPS_ = 1e-5f;

constexpr int WCATSZ = NFUSE_ * 128;   // 212992
constexpr int W1TSZ  = 512 * 128;      // 65536
constexpr int W2TSZ  = 512 * 128;      // 65536

__device__ __forceinline__ float gelu_f(float x) {
  return 0.5f * x * (1.0f + erff(x * 0.70710678118654752440f));
}

__device__ __forceinline__ void unpack8(const uint4 w, float* f) {
  f[0] = __uint_as_float(w.x << 16); f[1] = __uint_as_float(w.x & 0xFFFF0000u);
  f[2] = __uint_as_float(w.y << 16); f[3] = __uint_as_float(w.y & 0xFFFF0000u);
  f[4] = __uint_as_float(w.z << 16); f[5] = __uint_as_float(w.z & 0xFFFF0000u);
  f[6] = __uint_as_float(w.w << 16); f[7] = __uint_as_float(w.w & 0xFFFF0000u);
}

__device__ __forceinline__ float qk_dot(const uint4 kw, const uint4 qw, const float* qf) {
#ifdef HAVE_DOT2
  union U { unsigned u; bf16x2v v; };
  U a0, a1, a2, a3, b0, b1, b2, b3;
  a0.u = kw.x; a1.u = kw.y; a2.u = kw.z; a3.u = kw.w;
  b0.u = qw.x; b1.u = qw.y; b2.u = qw.z; b3.u = qw.w;
  float p = 0.f;
  p = __builtin_amdgcn_fdot2_f32_bf16(a0.v, b0.v, p, false);
  p = __builtin_amdgcn_fdot2_f32_bf16(a1.v, b1.v, p, false);
  p = __builtin_amdgcn_fdot2_f32_bf16(a2.v, b2.v, p, false);
  p = __builtin_amdgcn_fdot2_f32_bf16(a3.v, b3.v, p, false);
  return p;
#else
  float kf[8]; unpack8(kw, kf);
  return kf[0] * qf[0] + kf[1] * qf[1] + kf[2] * qf[2] + kf[3] * qf[3]
       + kf[4] * qf[4] + kf[5] * qf[5] + kf[6] * qf[6] + kf[7] * qf[7];
#endif
}

// ---------------- weight prep: LDS-tiled 32x32 transpose + bf16 cast ----------------
// 336 tiles/layer: Wq[0,64) Wk[64,128) Wv[128,192) Ws[192,208) W1[208,272) W2[272,336)
__global__ __launch_bounds__(256) void k_ptrans(
    const float* __restrict__ Wq, const float* __restrict__ Wk,
    const float* __restrict__ Wv, const float* __restrict__ Ws,
    const float* __restrict__ W1, const float* __restrict__ W2,
    bf16* __restrict__ Wcat, bf16* __restrict__ W1t, bf16* __restrict__ W2t) {
  __shared__ float lds[32][33];
  const int b = blockIdx.x;
  const int l = b / 336, t = b % 336;
  const float* src; int C; bf16* dst; int dld; int nof; int tt;
  if (t < 192) {        // Wq/Wk/Wv: [128][512] -> Wcat[n+off][kk]
    int which = t / 64; tt = t % 64;
    src = (which == 0 ? Wq : which == 1 ? Wk : Wv) + (size_t)l * 128 * 512;
    C = 512; dst = Wcat + (size_t)l * WCATSZ; dld = 128; nof = which * 512;
  } else if (t < 208) { // Ws: [128][128] -> Wcat[1536+n][kk]
    tt = t - 192;
    src = Ws + (size_t)l * 128 * 128; C = 128;
    dst = Wcat + (size_t)l * WCATSZ; dld = 128; nof = 1536;
  } else if (t < 272) { // W1: [128][512] -> W1t[n][kk] ld128
    tt = t - 208;
    src = W1 + (size_t)l * 128 * 512; C = 512;
    dst = W1t + (size_t)l * W1TSZ; dld = 128; nof = 0;
  } else {              // W2: [512][128] -> W2t[n][kk] ld512
    tt = t - 272;
    src = W2 + (size_t)l * 512 * 128; C = 128;
    dst = W2t + (size_t)l * W2TSZ; dld = 512; nof = 0;
  }
  const int tpr = C >> 5;
  const int r0 = (tt / tpr) * 32, c0 = (tt % tpr) * 32;
  const int j = threadIdx.x & 31, g = threadIdx.x >> 5;
#pragma unroll
  for (int ii = 0; ii < 4; ++ii) {
    int i = g * 4 + ii;
    lds[i][j] = src[(size_t)(r0 + i) * C + c0 + j];
  }
  __syncthreads();
#pragma unroll
  for (int ii = 0; ii < 4; ++ii) {
    int i = g * 4 + ii;
    dst[(size_t)(nof + c0 + i) * dld + r0 + j] = __float2bfloat16(lds[j][i]);
  }
}

__global__ void k_prepb(const float* __restrict__ bq, const float* __restrict__ bk,
                        const float* __restrict__ bv, const float* __restrict__ bs,
                        float* __restrict__ bcat) {
  int j = blockIdx.x * 256 + threadIdx.x;
  if (j < 5 * NFUSE_) {
    int l = j / NFUSE_, c = j % NFUSE_;
    float v = (c < 512)  ? bq[l * 512 + c]
            : (c < 1024) ? bk[l * 512 + c - 512]
            : (c < 1536) ? bv[l * 512 + c - 1024]
            :              bs[l * 128 + c - 1536];
    bcat[j] = v;
  }
}

// ---------------- embedding GEMM + fused BN partial stats ----------------
__global__ __launch_bounds__(256) void k_embed2(const float* __restrict__ x,
    const float* __restrict__ W, const float* __restrict__ b,
    float* __restrict__ out, float* __restrict__ ss, float* __restrict__ sq) {
  __shared__ float xs[128][16];
  __shared__ float wsm[16][128];
  __shared__ float sr[2][128], qr[2][128];
  const int blk = blockIdx.x;          // 128 blocks x 128 rows
  const int t = threadIdx.x;
  for (int i = t; i < 16 * 128; i += 256) wsm[i >> 7][i & 127] = W[i];
  for (int i = t; i < 128 * 16; i += 256) xs[i >> 4][i & 15] = x[(size_t)blk * 2048 + i];
  __syncthreads();
  const int c = t & 127, rg = t >> 7;
  float bc = b[c];
  float s = 0.f, q = 0.f;
  for (int r = rg * 64; r < rg * 64 + 64; ++r) {
    float v = bc;
#pragma unroll
    for (int f = 0; f < 16; ++f) v = fmaf(xs[r][f], wsm[f][c], v);
    out[(size_t)(blk * 128 + r) * 128 + c] = v;
    s += v; q += v * v;
  }
  sr[rg][c] = s; qr[rg][c] = q;
  __syncthreads();
  if (t < 128) { ss[blk * 128 + t] = sr[0][t] + sr[1][t]; sq[blk * 128 + t] = qr[0][t] + qr[1][t]; }
}

// ---------------- BatchNorm finalize / apply ----------------
template<int NC>
__global__ void k_bn_finalize(const float* __restrict__ sums, const float* __restrict__ sumsq,
                              const float* __restrict__ g, const float* __restrict__ be,
                              float* __restrict__ a, float* __restrict__ cc) {
  int c = blockIdx.x * 128 + threadIdx.x;
  if (c >= NC) return;
  float s = 0.f, q = 0.f;
  for (int b = 0; b < 128; ++b) { s += sums[b * NC + c]; q += sumsq[b * NC + c]; }
  float mean = s * (1.0f / N_);
  float var  = q * (1.0f / N_) - mean * mean;
  float inv  = rsqrtf(var + EPS_);
  float aa   = g[c] * inv;
  a[c]  = aa;
  cc[c] = be[c] - aa * mean;
}

// vectorized x4: one float4 in, 4 bf16 out per thread
template<int NC>
__global__ void k_bn_apply_gelu_cast(const float* __restrict__ xin, const float* __restrict__ a,
                                     const float* __restrict__ cc, bf16* __restrict__ outb) {
  int i4 = (blockIdx.x * 256 + threadIdx.x) * 4;
  int c = i4 & (NC - 1);
  float4 v = *reinterpret_cast<const float4*>(xin + i4);
  union { uint2 u2; bf16 h[4]; } pk;
  pk.h[0] = __float2bfloat16(gelu_f(fmaf(a[c + 0], v.x, cc[c + 0])));
  pk.h[1] = __float2bfloat16(gelu_f(fmaf(a[c + 1], v.y, cc[c + 1])));
  pk.h[2] = __float2bfloat16(gelu_f(fmaf(a[c + 2], v.z, cc[c + 2])));
  pk.h[3] = __float2bfloat16(gelu_f(fmaf(a[c + 3], v.w, cc[c + 3])));
  *reinterpret_cast<uint2*>(outb + i4) = pk.u2;
}

// ---------------- CSR build over dst ----------------
__global__ void k_count(const int* __restrict__ dst, int* __restrict__ deg) {
  int e = blockIdx.x * 256 + threadIdx.x;
  if (e < E_) atomicAdd(&deg[dst[e]], 1);
}

__global__ void k_bsum(const int* __restrict__ deg, int* __restrict__ bsum) {
  __shared__ int sh[256];
  int t = threadIdx.x;
  sh[t] = deg[blockIdx.x * 256 + t];
  __syncthreads();
  for (int d = 128; d > 0; d >>= 1) { if (t < d) sh[t] += sh[t + d]; __syncthreads(); }
  if (t == 0) bsum[blockIdx.x] = sh[0];
}

__global__ void k_btop(const int* __restrict__ bsum, int* __restrict__ btop) {
  int t = threadIdx.x;          // 64 threads, one wave
  int v = bsum[t];
  int s = v;
  for (int d = 1; d < 64; d <<= 1) { int o = __shfl_up(s, d); if (t >= d) s += o; }
  btop[t] = s - v;              // exclusive
}

__global__ void k_boffs(const int* __restrict__ deg, const int* __restrict__ btop,
                        int* __restrict__ offs) {
  __shared__ int sh[256];
  int t = threadIdx.x;
  int v = deg[blockIdx.x * 256 + t];
  sh[t] = v;
  __syncthreads();
  for (int d = 1; d < 256; d <<= 1) {
    int add = (t >= d) ? sh[t - d] : 0;
    __syncthreads();
    sh[t] += add;
    __syncthreads();
  }
  offs[blockIdx.x * 256 + t] = btop[blockIdx.x] + sh[t] - v;
  if (blockIdx.x == 63 && t == 255) offs[N_] = E_;
}

__global__ void k_scatter(const int* __restrict__ src, const int* __restrict__ dst,
                          const int* __restrict__ off, int* __restrict__ cursor,
                          int* __restrict__ srcs) {
  int e = blockIdx.x * 256 + threadIdx.x;
  if (e < E_) {
    int d = dst[e];
    int pos = off[d] + atomicAdd(&cursor[d], 1);
    srcs[pos] = src[e];
  }
}

// ---------------- bf16 MFMA GEMM: C[M,NOUT] = A[M,K] @ BT[NOUT,K]^T + bias ----------------
// MODE 0: fp32 out. MODE 1: fp32 + bf16 out. MODE 2: fused qkv routing.
// MODE 3: fp32 out + per-m-tile BN column partial stats.
template<int KDIM, int NOUT, int TM, int MODE>
__global__ __launch_bounds__(256) void k_mfma(
    const bf16* __restrict__ A, const bf16* __restrict__ BT,
    const float* __restrict__ bias,
    float* __restrict__ outF, bf16* __restrict__ outB,
    bf16* __restrict__ QKVp, float* __restrict__ xrp,
    float* __restrict__ ss, float* __restrict__ sq) {
  constexpr int MF = TM / 32;
  __shared__ bf16 As[TM][72];
  __shared__ bf16 Bs[128][72];
  __shared__ float sred[2][128], qred[2][128];
  const int tid = threadIdx.x;
  const int wid = tid >> 6, lane = tid & 63;
  const int wr = wid >> 1, wc = wid & 1;
  const int m0 = blockIdx.x * TM, n0 = blockIdx.y * 128;
  const int ln = lane & 15, lq = lane >> 4;
  f32x4 acc[MF][4];
#pragma unroll
  for (int i = 0; i < MF; ++i)
#pragma unroll
    for (int j = 0; j < 4; ++j) acc[i][j] = (f32x4){0.f, 0.f, 0.f, 0.f};

  for (int k0 = 0; k0 < KDIM; k0 += 64) {
#pragma unroll
    for (int u = tid; u < TM * 8; u += 256) {
      int r = u >> 3, c = u & 7;
      *(uint4*)(&As[r][c * 8]) = *(const uint4*)(A + (size_t)(m0 + r) * KDIM + k0 + c * 8);
    }
#pragma unroll
    for (int u = tid; u < 1024; u += 256) {
      int r = u >> 3, c = u & 7;
      *(uint4*)(&Bs[r][c * 8]) = *(const uint4*)(BT + (size_t)(n0 + r) * KDIM + k0 + c * 8);
    }
    __syncthreads();
#pragma unroll
    for (int kk = 0; kk < 2; ++kk) {
      bf16x8 af[MF], bg[4];
#pragma unroll
      for (int i = 0; i < MF; ++i)
        af[i] = *(const bf16x8*)(&As[wr * (TM / 2) + i * 16 + ln][kk * 32 + lq * 8]);
#pragma unroll
      for (int j = 0; j < 4; ++j)
        bg[j] = *(const bf16x8*)(&Bs[wc * 64 + j * 16 + ln][kk * 32 + lq * 8]);
#pragma unroll
      for (int i = 0; i < MF; ++i)
#pragma unroll
        for (int j = 0; j < 4; ++j)
          acc[i][j] = __builtin_amdgcn_mfma_f32_16x16x32_bf16(af[i], bg[j], acc[i][j], 0, 0, 0);
    }
    __syncthreads();
  }
  float ssj[4] = {0.f, 0.f, 0.f, 0.f}, sqj[4] = {0.f, 0.f, 0.f, 0.f};
#pragma unroll
  for (int i = 0; i < MF; ++i) {
#pragma unroll
    for (int j = 0; j < 4; ++j) {
      int gcol = n0 + wc * 64 + j * 16 + ln;
      float bv = bias[gcol];
      int row0 = m0 + wr * (TM / 2) + i * 16 + lq * 4;
#pragma unroll
      for (int qq = 0; qq < 4; ++qq) {
        float val = acc[i][j][qq] + bv;
        int row = row0 + qq;
        if (MODE == 0 || MODE == 3) {
          outF[(size_t)row * NOUT + gcol] = val;
          if (MODE == 3) { ssj[j] += val; sqj[j] += val * val; }
        } else if (MODE == 1) {
          outF[(size_t)row * NOUT + gcol] = val;
          outB[(size_t)row * NOUT + gcol] = __float2bfloat16(val);
        } else {
          if (n0 < 1536) QKVp[(size_t)row * QKV3_ + gcol] = __float2bfloat16(val);
          else           xrp[(size_t)row * H_ + (gcol - 1536)] = val;
        }
      }
    }
  }
  if constexpr (MODE == 3) {
#pragma unroll
    for (int j = 0; j < 4; ++j) {
      ssj[j] += __shfl_xor(ssj[j], 16); ssj[j] += __shfl_xor(ssj[j], 32);
      sqj[j] += __shfl_xor(sqj[j], 16); sqj[j] += __shfl_xor(sqj[j], 32);
    }
    if (lq == 0) {
#pragma unroll
      for (int j = 0; j < 4; ++j) {
        sred[wr][wc * 64 + j * 16 + ln] = ssj[j];
        qred[wr][wc * 64 + j * 16 + ln] = sqj[j];
      }
    }
    __syncthreads();
    if (tid < 128) {
      ss[(size_t)blockIdx.x * NOUT + n0 + tid] = sred[0][tid] + sred[1][tid];
      sq[(size_t)blockIdx.x * NOUT + n0 + tid] = qred[0][tid] + qred[1][tid];
    }
  }
}

// ---------------- fused attention + beta gate (one wave per dst node) ----------------
__global__ __launch_bounds__(256) void k_attn(const bf16* __restrict__ QKV,
    const float* __restrict__ xr, const float* __restrict__ Wb,
    const int* __restrict__ srcs, const int* __restrict__ off,
    bf16* __restrict__ gated) {
  const int wave = threadIdx.x >> 6;
  const int lane = threadIdx.x & 63;
  // XCD-aware swizzle: each XCD gets a contiguous 2048-node chunk
  const int bid = blockIdx.x;
  const int swz = ((bid & 7) << 9) | (bid >> 3);   // 4096 blocks, bijective
  const int node = swz * 4 + wave;
  const float scale = 0.08838834764831845f;   // 1/sqrt(128)
  const uint4* qp = reinterpret_cast<const uint4*>(QKV + (size_t)node * QKV3_);
  uint4 qw = qp[lane];
  float qf[8];
#ifndef HAVE_DOT2
  unpack8(qw, qf);
#else
  qf[0] = 0.f;   // unused
#endif
  float m = -1e30f, den = 0.f;
  float acc[8] = {0.f, 0.f, 0.f, 0.f, 0.f, 0.f, 0.f, 0.f};
  const int s0 = off[node], s1 = off[node + 1];
  if (s0 < s1) {
    int i0 = srcs[s0];
    int i1 = (s0 + 1 < s1) ? srcs[s0 + 1] : i0;
    const uint4* p0 = reinterpret_cast<const uint4*>(QKV + (size_t)i0 * QKV3_ + 512) + lane;
    const uint4* p1 = reinterpret_cast<const uint4*>(QKV + (size_t)i1 * QKV3_ + 512) + lane;
    uint4 k0 = p0[0], v0 = p0[64];
    uint4 k1 = p1[0], v1 = p1[64];
    for (int t = s0; t < s1; t += 2) {
      // prefetch edges t+2, t+3 (clamped addresses -> cache hits on tail)
      int j0 = (t + 2 < s1) ? srcs[t + 2] : i0;
      int j1 = (t + 3 < s1) ? srcs[t + 3] : i0;
      const uint4* q0 = reinterpret_cast<const uint4*>(QKV + (size_t)j0 * QKV3_ + 512) + lane;
      const uint4* q1 = reinterpret_cast<const uint4*>(QKV + (size_t)j1 * QKV3_ + 512) + lane;
      uint4 nk0 = q0[0], nv0 = q0[64];
      uint4 nk1 = q1[0], nv1 = q1[64];
      {
        float p = qk_dot(k0, qw, qf);
        p += __shfl_xor(p, 1); p += __shfl_xor(p, 2);
        p += __shfl_xor(p, 4); p += __shfl_xor(p, 8);
        float logit = p * scale;
        if (logit > m + 8.f) {        // defer-max: rescale only on big jumps
          float co = __expf(m - logit);
          den *= co;
#pragma unroll
          for (int j = 0; j < 8; ++j) acc[j] *= co;
          m = logit;
        }
        float pe = __expf(logit - m);
        den += pe;
        float vf[8]; unpack8(v0, vf);
#pragma unroll
        for (int j = 0; j < 8; ++j) acc[j] = fmaf(pe, vf[j], acc[j]);
      }
      if (t + 1 < s1) {
        float p = qk_dot(k1, qw, qf);
        p += __shfl_xor(p, 1); p += __shfl_xor(p, 2);
        p += __shfl_xor(p, 4); p += __shfl_xor(p, 8);
        float logit = p * scale;
        if (logit > m + 8.f) {
          float co = __expf(m - logit);
          den *= co;
#pragma unroll
          for (int j = 0; j < 8; ++j) acc[j] *= co;
          m = logit;
        }
        float pe = __expf(logit - m);
        den += pe;
        float vf[8]; unpack8(v1, vf);
#pragma unroll
        for (int j = 0; j < 8; ++j) acc[j] = fmaf(pe, vf[j], acc[j]);
      }
      k0 = nk0; v0 = nv0; k1 = nk1; v1 = nv1;
    }
  }
  float inv = 1.f / (den + 1e-16f);
  float r[8];
#pragma unroll
  for (int j = 0; j < 8; ++j) {
    r[j] = acc[j] * inv;
    r[j] += __shfl_xor(r[j], 16);
    r[j] += __shfl_xor(r[j], 32);
    r[j] *= 0.25f;                 // mean over 4 heads; all lanes hold result
  }
  // fused beta gate
  const int c0 = (lane & 15) * 8;
  float xv[8];
  const float* xp = xr + (size_t)node * H_ + c0;
#pragma unroll
  for (int j = 0; j < 8; ++j) xv[j] = xp[j];
  float s = 0.f;
#pragma unroll
  for (int j = 0; j < 8; ++j) {
    int c = c0 + j;
    s += r[j] * (Wb[c] + Wb[256 + c]) + xv[j] * (Wb[128 + c] - Wb[256 + c]);
  }
  s += __shfl_xor(s, 1); s += __shfl_xor(s, 2);
  s += __shfl_xor(s, 4); s += __shfl_xor(s, 8);
  float beta = 1.f / (1.f + __expf(-s));
  if (lane < 16) {
    union { uint4 u4; bf16 h[8]; } pk;
#pragma unroll
    for (int j = 0; j < 8; ++j) pk.h[j] = __float2bfloat16(beta * xv[j] + (1.f - beta) * r[j]);
    *reinterpret_cast<uint4*>(gated + (size_t)node * H_ + c0) = pk.u4;
  }
}

// ---------------- graph max-pool + prediction ----------------
__global__ void k_pool_init(unsigned int* __restrict__ pooled) {
  int i = blockIdx.x * 64 + threadIdx.x;
  if (i < G_ * H_) pooled[i] = 0x007FFFFFu;
}

__global__ void k_pool(const float* __restrict__ h, const int* __restrict__ batch,
                       unsigned int* __restrict__ pooled) {
  int idx = blockIdx.x * 256 + threadIdx.x;
  int n = idx >> 7, c = idx & 127;
  unsigned u = __float_as_uint(h[idx]);
  u = (u & 0x80000000u) ? ~u : (u | 0x80000000u);
  atomicMax(&pooled[batch[n] * H_ + c], u);
}

__global__ void k_pred(const unsigned int* __restrict__ pooled, const float* __restrict__ predW,
                       const float* __restrict__ predb, float* __restrict__ out) {
  int g = blockIdx.x;
  int lane = threadIdx.x;
  float s = 0.f;
  for (int c = lane; c < H_; c += 64) {
    unsigned u = pooled[g * H_ + c];
    u = (u & 0x80000000u) ? (u & 0x7FFFFFFFu) : ~u;
    s += __uint_as_float(u) * predW[c];
  }
#pragma unroll
  for (int d = 1; d < 64; d <<= 1) s += __shfl_xor(s, d);
  if (lane == 0) out[g] = s + predb[0];
}

extern "C" void kernel_launch(void* const* d_in, const int* in_sizes, int n_in,
                              void* d_out, int out_size, void* d_ws, size_t ws_size,
                              hipStream_t stream) {
  const float* x      = (const float*)d_in[0];
  const int*   edge   = (const int*)d_in[1];
  const int*   esrc   = edge;
  const int*   edst   = edge + E_;
  const int*   batch  = (const int*)d_in[2];
  const float* embW   = (const float*)d_in[3];
  const float* embb   = (const float*)d_in[4];
  const float* emb_g  = (const float*)d_in[5];
  const float* emb_be = (const float*)d_in[6];
  const float* Wq     = (const float*)d_in[7];
  const float* bq     = (const float*)d_in[8];
  const float* Wk     = (const float*)d_in[9];
  const float* bk     = (const float*)d_in[10];
  const float* Wv     = (const float*)d_in[11];
  const float* bv     = (const float*)d_in[12];
  const float* Wskip  = (const float*)d_in[13];
  const float* bskip  = (const float*)d_in[14];
  const float* Wbeta  = (const float*)d_in[15];
  const float* W1     = (const float*)d_in[16];
  const float* b1     = (const float*)d_in[17];
  const float* g1     = (const float*)d_in[18];
  const float* be1    = (const float*)d_in[19];
  const float* W2     = (const float*)d_in[20];
  const float* b2     = (const float*)d_in[21];
  const float* predW  = (const float*)d_in[22];
  const float* predb  = (const float*)d_in[23];

  // ---- workspace layout ----
  float* ws = (float*)d_ws;
  size_t o = 0;
  auto alloc_f = [&](size_t n) { float* p = ws + o; o += n; return p; };
  float* h32   = alloc_f((size_t)N_ * H_);
  float* t1    = alloc_f((size_t)N_ * DFF_);
  float* xr    = alloc_f((size_t)N_ * H_);
  float* stats = alloc_f(2 * 128 * DFF_);
  float* a_c   = alloc_f(DFF_);
  float* c_c   = alloc_f(DFF_);
  float* bcat  = alloc_f(5 * NFUSE_);
  bf16* bp = (bf16*)(ws + o);
  size_t ob = 0;
  auto alloc_b = [&](size_t n) { bf16* p = bp + ob; ob += n; return p; };
  bf16* QKV  = alloc_b((size_t)N_ * QKV3_);
  bf16* hb   = alloc_b((size_t)N_ * H_);
  bf16* gated= alloc_b((size_t)N_ * H_);
  bf16* t1b  = alloc_b((size_t)N_ * DFF_);
  bf16* Wcat = alloc_b((size_t)5 * WCATSZ);
  bf16* W1t  = alloc_b((size_t)5 * W1TSZ);
  bf16* W2t  = alloc_b((size_t)5 * W2TSZ);
  unsigned int* pooled = (unsigned int*)(bp + ob);
  int* deg    = (int*)(pooled + G_ * H_);
  int* offs   = deg + N_;
  int* cursor = offs + N_ + 1;
  int* srcs   = cursor + N_;
  int* bsum   = srcs + E_;       // 64
  int* btop   = bsum + 64;       // 64

  // ---- weight prep (tiled transpose + bias concat) ----
  k_ptrans<<<5 * 336, 256, 0, stream>>>(Wq, Wk, Wv, Wskip, W1, W2, Wcat, W1t, W2t);
  k_prepb<<<(5 * NFUSE_ + 255) / 256, 256, 0, stream>>>(bq, bk, bv, bskip, bcat);

  // ---- CSR build (hierarchical scan) ----
  hipMemsetAsync(deg, 0, N_ * sizeof(int), stream);
  hipMemsetAsync(cursor, 0, N_ * sizeof(int), stream);
  k_count  <<<E_ / 256, 256, 0, stream>>>(edst, deg);
  k_bsum   <<<64, 256, 0, stream>>>(deg, bsum);
  k_btop   <<<1, 64, 0, stream>>>(bsum, btop);
  k_boffs  <<<64, 256, 0, stream>>>(deg, btop, offs);
  k_scatter<<<E_ / 256, 256, 0, stream>>>(esrc, edst, offs, cursor, srcs);

  // ---- embedding (+fused stats) + BN + GELU -> bf16 ----
  k_embed2<<<128, 256, 0, stream>>>(x, embW, embb, t1, stats, stats + 128 * 128);
  k_bn_finalize<128><<<1, 128, 0, stream>>>(stats, stats + 128 * 128, emb_g, emb_be, a_c, c_c);
  k_bn_apply_gelu_cast<128><<<N_ * H_ / 1024, 256, 0, stream>>>(t1, a_c, c_c, hb);

  for (int l = 0; l < L_; ++l) {
    const float* Wb_ = Wbeta + (size_t)l * 3 * H_;
    const float* b1_ = b1 + (size_t)l * DFF_;
    const float* g1_ = g1 + (size_t)l * DFF_;
    const float* be1_= be1 + (size_t)l * DFF_;
    const float* b2_ = b2 + (size_t)l * H_;

    k_mfma<128, NFUSE_, 128, 2><<<dim3(N_ / 128, NFUSE_ / 128), 256, 0, stream>>>(
        hb, Wcat + (size_t)l * WCATSZ, bcat + (size_t)l * NFUSE_,
        nullptr, nullptr, QKV, xr, nullptr, nullptr);

    k_attn<<<N_ / 4, 256, 0, stream>>>(QKV, xr, Wb_, srcs, offs, gated);

    k_mfma<128, 512, 128, 3><<<dim3(N_ / 128, 4), 256, 0, stream>>>(
        gated, W1t + (size_t)l * W1TSZ, b1_, t1, nullptr, nullptr, nullptr,
        stats, stats + 128 * 512);

    k_bn_finalize<512><<<4, 128, 0, stream>>>(stats, stats + 128 * 512, g1_, be1_, a_c, c_c);
    k_bn_apply_gelu_cast<512><<<N_ * DFF_ / 1024, 256, 0, stream>>>(t1, a_c, c_c, t1b);

    k_mfma<512, 128, 64, 1><<<dim3(N_ / 64, 1), 256, 0, stream>>>(
        t1b, W2t + (size_t)l * W2TSZ, b2_, h32, hb, nullptr, nullptr, nullptr, nullptr);
  }

  // ---- pooling + prediction ----
  k_pool_init<<<G_ * H_ / 64, 64, 0, stream>>>(pooled);
  k_pool<<<N_ * H_ / 256, 256, 0, stream>>>(h32, batch, pooled);
  k_pred<<<G_, 64, 0, stream>>>(pooled, predW, predb, (float*)d_out);
}